// Round 7
// baseline (24525.755 us; speedup 1.0000x reference)
//
#include <hip/hip_runtime.h>

typedef unsigned short u16;
typedef __attribute__((ext_vector_type(8))) short short8;   // 8 x bf16 (4 VGPRs)
typedef __attribute__((ext_vector_type(4))) float f32x4;

#define HALFN 2016

__device__ __forceinline__ u16 f2b_rn(float x) {         // round-nearest-even
    union { float f; unsigned u; } v; v.f = x;
    unsigned r = v.u + 0x7FFFu + ((v.u >> 16) & 1u);
    return (u16)(r >> 16);
}

__device__ __forceinline__ void gll16(const void* g, void* s) {
    __builtin_amdgcn_global_load_lds(
        (const __attribute__((address_space(1))) unsigned int*)g,
        (__attribute__((address_space(3))) unsigned int*)s, 16, 0, 0);
}

// Grid barrier for an exactly-resident 512-block grid.  Counter cells live in
// the OUT buffer (harness memsets out=0 before every launch), target is the
// constant 512.  Release: device fence + one atomicAdd per block.  Acquire:
// bounded agent-scope-load spin + fence.  Bounded spin => any sync bug
// degrades to a wrong answer, never a hung container.
__device__ __forceinline__ void gbar(unsigned* ctr) {
    __threadfence();
    __syncthreads();
    if (threadIdx.x == 0) {
        atomicAdd(ctr, 1u);
        int spins = 0;
        while (__hip_atomic_load(ctr, __ATOMIC_RELAXED, __HIP_MEMORY_SCOPE_AGENT) != 512u
               && spins < 50000) {
            __builtin_amdgcn_s_sleep(2);
            ++spins;
        }
    }
    __syncthreads();
    __threadfence();
}

// Shared-memory union: phases are strictly sequential.  Max member 51.5 KB
// -> 2 blocks/CU uses 103 KB of 160 KB LDS (comfortable residency slack).
union SmemU {
    u16 g[2][12288];    // proj: 2x(A1|A2|B 64x64); out: 2x(A|B) uses 8192 each
    float pw[64][65];   // phase 0 Pw transpose tile
    struct { float Ms[64][65]; float Gs[64][68]; float Ts[64][68]; } tu;
};

// ---------------------------------------------------------------------------
// Single persistent kernel, 512 blocks x 256 threads (exactly 2 blocks/CU).
//   0: LN 16 rows/block -> Xh; blocks 0..63 also Pw transpose; S-zero slice.
//   1: proj GEMM (both seqs) + Gram partial -> S   [R3/R5 proven body]
//   2: M build, T = M@G, 16-mixer-row U chunk -> UTh
//   3: out = PP1 @ UT^T + bias
// ---------------------------------------------------------------------------
__global__ __launch_bounds__(256, 2) void mega(
    const float* __restrict__ x1, const float* __restrict__ x2,
    const float* __restrict__ gamma, const float* __restrict__ beta,
    const float* __restrict__ proj, const float* __restrict__ halves,
    const float* __restrict__ diagonals, const float* __restrict__ Wm,
    const float* __restrict__ bmix,
    u16* __restrict__ Xh, u16* __restrict__ Pwh, u16* __restrict__ PPh,
    u16* __restrict__ UTh, float* __restrict__ S, float* __restrict__ out)
{
    __shared__ __align__(16) SmemU sm;
    const int bid = blockIdx.x, t = threadIdx.x;
    const int lane = t & 63, w = t >> 6;
    unsigned* flags = (unsigned*)out;    // out memset 0 before every launch

    // ===================== phase 0: LN + Pw prep + S zero =====================
    {
        if (t < 128) S[(size_t)bid * 128 + t] = 0.f;

        const float4 g0 = *(const float4*)&gamma[lane * 4];
        const float4 g1 = *(const float4*)&gamma[256 + lane * 4];
        const float4 b0 = *(const float4*)&beta[lane * 4];
        const float4 b1 = *(const float4*)&beta[256 + lane * 4];

        #pragma unroll
        for (int r = w; r < 16; r += 4) {                // wave per row
            const int row = bid * 16 + r;                // 0..8191
            const float* src = (row < 4096) ? (x1 + (size_t)row * 512)
                                            : (x2 + (size_t)(row - 4096) * 512);
            float4 v0 = *(const float4*)&src[lane * 4];
            float4 v1 = *(const float4*)&src[256 + lane * 4];
            float s  = v0.x + v0.y + v0.z + v0.w + v1.x + v1.y + v1.z + v1.w;
            float sq = v0.x * v0.x + v0.y * v0.y + v0.z * v0.z + v0.w * v0.w +
                       v1.x * v1.x + v1.y * v1.y + v1.z * v1.z + v1.w * v1.w;
            #pragma unroll
            for (int off = 32; off > 0; off >>= 1) {
                s  += __shfl_down(s, off);
                sq += __shfl_down(sq, off);
            }
            s  = __shfl(s, 0);
            sq = __shfl(sq, 0);
            float mu  = s * (1.0f / 512.0f);
            float var = sq * (1.0f / 512.0f) - mu * mu;
            float rs  = rsqrtf(var + 1e-5f);
            ushort4 h0, h1;
            h0.x = f2b_rn((v0.x - mu) * rs * g0.x + b0.x);
            h0.y = f2b_rn((v0.y - mu) * rs * g0.y + b0.y);
            h0.z = f2b_rn((v0.z - mu) * rs * g0.z + b0.z);
            h0.w = f2b_rn((v0.w - mu) * rs * g0.w + b0.w);
            h1.x = f2b_rn((v1.x - mu) * rs * g1.x + b1.x);
            h1.y = f2b_rn((v1.y - mu) * rs * g1.y + b1.y);
            h1.z = f2b_rn((v1.z - mu) * rs * g1.z + b1.z);
            h1.w = f2b_rn((v1.w - mu) * rs * g1.w + b1.w);
            *(ushort4*)&Xh[(size_t)row * 512 + lane * 4] = h0;
            *(ushort4*)&Xh[(size_t)row * 512 + 256 + lane * 4] = h1;
        }

        if (bid < 64) {                                  // 64 Pw tiles
            const int n = bid >> 3, c0 = (bid & 7) * 64;
            #pragma unroll
            for (int i = 0; i < 4; i++) {
                int flat = i * 256 + t;
                int c = flat >> 4, k4 = (flat & 15) * 4;
                float4 v = *(const float4*)&proj[(size_t)n * 32768 + (size_t)(c0 + c) * 64 + k4];
                sm.pw[c][k4 + 0] = v.x; sm.pw[c][k4 + 1] = v.y;
                sm.pw[c][k4 + 2] = v.z; sm.pw[c][k4 + 3] = v.w;
            }
            __syncthreads();
            #pragma unroll
            for (int i = 0; i < 16; i++) {
                int flat = i * 256 + t;
                int k = flat >> 6, c = flat & 63;
                Pwh[(size_t)(n * 64 + k) * 512 + c0 + c] = f2b_rn(sm.pw[c][k]);
            }
        }
    }
    gbar(&flags[0]);

    // ========== phase 1: proj GEMM (both seqs) + Gram partial -> S ==========
    {
        const int bx = bid & 63, n = bid >> 6;           // XCD = bid%8 = bx%8
        const int b = bx >> 5, v0 = (bx & 31) * 64;
        const u16* A1 = Xh + (size_t)(b * 2048 + v0) * 512;      // x1 rows
        const u16* A2 = A1 + (size_t)4096 * 512;                 // x2 rows
        const u16* Bp = Pwh + (size_t)(n * 64) * 512;
        const int wm = w & 1, wn = w >> 1;
        const int fr = lane & 15, q = lane >> 4;

        int aoff[2][2], boff[2][2];
        #pragma unroll
        for (int kc = 0; kc < 2; kc++) {
            #pragma unroll
            for (int i = 0; i < 2; i++) {
                int r = wm * 32 + i * 16 + fr;
                aoff[kc][i] = r * 64 + (((kc * 4 + q) ^ (r & 7)) * 8);
            }
            #pragma unroll
            for (int j = 0; j < 2; j++) {
                int r = wn * 32 + j * 16 + fr;
                boff[kc][j] = r * 64 + (((kc * 4 + q) ^ (r & 7)) * 8);
            }
        }

        auto stage = [&](int kt, u16* buf) {     // 6 global_load_lds / thread
            #pragma unroll
            for (int p = 0; p < 2; p++) {
                int o = p * 4096 + t * 16;
                int r = o >> 7;
                int c = ((o >> 4) & 7) ^ (r & 7);
                size_t g = (size_t)r * 512 + kt + c * 8;
                gll16(A1 + g, buf + (o >> 1));
                gll16(A2 + g, buf + 4096 + (o >> 1));
                gll16(Bp + g, buf + 8192 + (o >> 1));
            }
        };

        f32x4 acc1[2][2] = {}, acc2[2][2] = {};
        stage(0, sm.g[0]);
        __syncthreads();
        for (int k = 0; k < 8; k++) {
            u16* cur = sm.g[k & 1];
            if (k < 7) stage((k + 1) * 64, sm.g[(k & 1) ^ 1]);
            #pragma unroll
            for (int kc = 0; kc < 2; kc++) {
                short8 a1f[2], a2f[2], bf[2];
                #pragma unroll
                for (int i = 0; i < 2; i++) {
                    a1f[i] = *(const short8*)(cur + aoff[kc][i]);
                    a2f[i] = *(const short8*)(cur + 4096 + aoff[kc][i]);
                }
                #pragma unroll
                for (int j = 0; j < 2; j++)
                    bf[j] = *(const short8*)(cur + 8192 + boff[kc][j]);
                #pragma unroll
                for (int i = 0; i < 2; i++)
                    #pragma unroll
                    for (int j = 0; j < 2; j++) {
                        acc1[i][j] = __builtin_amdgcn_mfma_f32_16x16x32_bf16(a1f[i], bf[j], acc1[i][j], 0, 0, 0);
                        acc2[i][j] = __builtin_amdgcn_mfma_f32_16x16x32_bf16(a2f[i], bf[j], acc2[i][j], 0, 0, 0);
                    }
            }
            __syncthreads();
        }

        // epilogue: PPh (x1 natural) + transposed bf16 tiles into buf0.
        u16* lds = sm.g[0];
        #pragma unroll
        for (int i = 0; i < 2; i++) {
            const int mloc = wm * 32 + i * 16 + q * 4;
            #pragma unroll
            for (int j = 0; j < 2; j++) {
                const int c = wn * 32 + j * 16 + fr;     // head-local column
                u16 h1[4], h2[4];
                #pragma unroll
                for (int r = 0; r < 4; r++) {
                    h1[r] = f2b_rn(acc1[i][j][r]);
                    h2[r] = f2b_rn(acc2[i][j][r]);
                }
                #pragma unroll
                for (int r = 0; r < 4; r++)
                    PPh[(size_t)(b * 2048 + v0 + mloc + r) * 512 + n * 64 + c] = h1[r];
                const int sw = c * 64 + (((mloc >> 3) ^ (c & 7)) * 8) + (mloc & 7);
                ushort4 u1; u1.x = h1[0]; u1.y = h1[1]; u1.z = h1[2]; u1.w = h1[3];
                ushort4 u2; u2.x = h2[0]; u2.y = h2[1]; u2.z = h2[2]; u2.w = h2[3];
                *(ushort4*)&lds[sw] = u1;                // T1
                *(ushort4*)&lds[4096 + sw] = u2;         // T2
            }
        }
        __syncthreads();

        // partial Gram: G[j][k] = sum_{v local} T2[j][v] * T1[k][v]
        f32x4 accg[2][2] = {};
        #pragma unroll
        for (int ks = 0; ks < 2; ks++) {
            short8 ag[2], bg[2];
            #pragma unroll
            for (int i = 0; i < 2; i++) {
                int jr = wm * 32 + i * 16 + fr;
                ag[i] = *(const short8*)&lds[4096 + jr * 64 + (((ks * 4 + q) ^ (jr & 7)) * 8)];
            }
            #pragma unroll
            for (int j = 0; j < 2; j++) {
                int kr = wn * 32 + j * 16 + fr;
                bg[j] = *(const short8*)&lds[kr * 64 + (((ks * 4 + q) ^ (kr & 7)) * 8)];
            }
            #pragma unroll
            for (int i = 0; i < 2; i++)
                #pragma unroll
                for (int j = 0; j < 2; j++)
                    accg[i][j] = __builtin_amdgcn_mfma_f32_16x16x32_bf16(ag[i], bg[j], accg[i][j], 0, 0, 0);
        }
        float* Sb = S + (size_t)(b * 8 + n) * 4096;
        #pragma unroll
        for (int i = 0; i < 2; i++) {
            int jrow = wm * 32 + i * 16 + q * 4;
            #pragma unroll
            for (int j = 0; j < 2; j++) {
                int kk = wn * 32 + j * 16 + fr;
                #pragma unroll
                for (int r = 0; r < 4; r++)
                    atomicAdd(&Sb[(jrow + r) * 64 + kk], accg[i][j][r]);
            }
        }
    }
    gbar(&flags[16]);

    // ============== phase 2: M build, T = M@G, U chunk -> UTh ==============
    {
        const int bn = bid >> 5, sub = bid & 31;
        const int b = bn >> 3, n = bn & 7;

        for (int idx = t; idx < 4096; idx += 256) {
            int r = idx >> 6, c = idx & 63;
            float val;
            if (r == c) {
                val = diagonals[n * 64 + r];
            } else {
                int rr = (r < c) ? r : c;
                int cc = (r < c) ? c : r;
                int h = rr * 63 - (rr * (rr - 1)) / 2 + (cc - rr - 1);
                val = halves[n * HALFN + h];
            }
            sm.tu.Ms[r][c] = val;
        }
        for (int idx = t; idx < 4096; idx += 256)
            sm.tu.Gs[idx >> 6][idx & 63] = S[(size_t)bn * 4096 + idx];
        __syncthreads();

        {   // T = M @ G : thread (k = t&63) computes chunk lq = t>>6 (16 cols)
            const int k = t & 63, lq = t >> 6;
            float a[16] = {};
            for (int j = 0; j < 64; j++) {
                float m = sm.tu.Ms[k][j];
                const float* gp = &sm.tu.Gs[j][lq * 16];
                #pragma unroll
                for (int u4 = 0; u4 < 4; u4++) {
                    float4 g4 = *(const float4*)&gp[u4 * 4];
                    a[u4 * 4 + 0] = fmaf(m, g4.x, a[u4 * 4 + 0]);
                    a[u4 * 4 + 1] = fmaf(m, g4.y, a[u4 * 4 + 1]);
                    a[u4 * 4 + 2] = fmaf(m, g4.z, a[u4 * 4 + 2]);
                    a[u4 * 4 + 3] = fmaf(m, g4.w, a[u4 * 4 + 3]);
                }
            }
            int pos = (lq ^ (k & 3)) * 16;               // swizzled chunk slot
            #pragma unroll
            for (int u4 = 0; u4 < 4; u4++) {
                float4 v4 = {a[u4 * 4 + 0], a[u4 * 4 + 1], a[u4 * 4 + 2], a[u4 * 4 + 3]};
                *(float4*)&sm.tu.Ts[k][pos + u4 * 4] = v4;
            }
        }
        __syncthreads();

        const int k2 = t & 63, cgp = t >> 6;
        const int c0 = sub * 16 + cgp * 4;               // 4 mixer rows/group
        float uacc[4] = {};
        #pragma unroll
        for (int kkc = 0; kkc < 4; kkc++) {
            const float* tp = &sm.tu.Ts[k2][(kkc ^ (k2 & 3)) * 16];
            float ts[16];
            #pragma unroll
            for (int u = 0; u < 4; u++) {
                float4 t4 = *(const float4*)&tp[u * 4];
                ts[u * 4 + 0] = t4.x; ts[u * 4 + 1] = t4.y;
                ts[u * 4 + 2] = t4.z; ts[u * 4 + 3] = t4.w;
            }
            #pragma unroll
            for (int i = 0; i < 4; i++) {
                const float* wrow = &Wm[(size_t)(c0 + i) * 512 + n * 64 + kkc * 16];
                #pragma unroll
                for (int u = 0; u < 4; u++) {
                    float4 w4 = *(const float4*)&wrow[u * 4];
                    uacc[i] = fmaf(ts[u * 4 + 0], w4.x, uacc[i]);
                    uacc[i] = fmaf(ts[u * 4 + 1], w4.y, uacc[i]);
                    uacc[i] = fmaf(ts[u * 4 + 2], w4.z, uacc[i]);
                    uacc[i] = fmaf(ts[u * 4 + 3], w4.w, uacc[i]);
                }
            }
        }
        #pragma unroll
        for (int i = 0; i < 4; i++)
            UTh[(size_t)b * 262144 + (size_t)(c0 + i) * 512 + n * 64 + k2] = f2b_rn(uacc[i]);
    }
    gbar(&flags[32]);

    // ================= phase 3: out = PP1 @ UT^T + bias =================
    {
        const int m0 = (bid & 31) * 64;                  // XCD = bid%8
        const int n0 = ((bid >> 5) & 7) * 64;
        const int b = bid >> 8;
        const u16* A  = PPh + (size_t)b * 2048 * 512;
        const u16* Bu = UTh + (size_t)b * 512 * 512;
        const int wm = w & 1, wn = w >> 1;
        const int fr = lane & 15, q = lane >> 4;

        int aoff[2][2], boff[2][2];
        #pragma unroll
        for (int kc = 0; kc < 2; kc++) {
            #pragma unroll
            for (int i = 0; i < 2; i++) {
                int r = wm * 32 + i * 16 + fr;
                aoff[kc][i] = r * 64 + (((kc * 4 + q) ^ (r & 7)) * 8);
            }
            #pragma unroll
            for (int j = 0; j < 2; j++) {
                int r = wn * 32 + j * 16 + fr;
                boff[kc][j] = r * 64 + (((kc * 4 + q) ^ (r & 7)) * 8);
            }
        }

        auto stage = [&](int kt, u16* buf) {     // 4 global_load_lds / thread
            #pragma unroll
            for (int p = 0; p < 2; p++) {
                int o = p * 4096 + t * 16;
                int r = o >> 7;
                int c = ((o >> 4) & 7) ^ (r & 7);
                gll16(A  + (size_t)(m0 + r) * 512 + kt + c * 8, buf + (o >> 1));
                gll16(Bu + (size_t)(n0 + r) * 512 + kt + c * 8, buf + 4096 + (o >> 1));
            }
        };

        f32x4 acc[2][2] = {};
        stage(0, sm.g[0]);
        __syncthreads();
        for (int k = 0; k < 8; k++) {
            u16* cur = sm.g[k & 1];
            if (k < 7) stage((k + 1) * 64, sm.g[(k & 1) ^ 1]);
            #pragma unroll
            for (int kc = 0; kc < 2; kc++) {
                short8 af[2], bf[2];
                #pragma unroll
                for (int i = 0; i < 2; i++)
                    af[i] = *(const short8*)(cur + aoff[kc][i]);
                #pragma unroll
                for (int j = 0; j < 2; j++)
                    bf[j] = *(const short8*)(cur + 4096 + boff[kc][j]);
                #pragma unroll
                for (int i = 0; i < 2; i++)
                    #pragma unroll
                    for (int j = 0; j < 2; j++)
                        acc[i][j] = __builtin_amdgcn_mfma_f32_16x16x32_bf16(af[i], bf[j], acc[i][j], 0, 0, 0);
            }
            __syncthreads();
        }

        #pragma unroll
        for (int i = 0; i < 2; i++) {
            int m = m0 + wm * 32 + i * 16 + q * 4;
            #pragma unroll
            for (int j = 0; j < 2; j++) {
                int n = n0 + wn * 32 + j * 16 + fr;
                float bv = bmix[n];
                #pragma unroll
                for (int r = 0; r < 4; r++)
                    out[(size_t)(b * 2048 + m + r) * 512 + n] = acc[i][j][r] + bv;
            }
        }
    }
}

// ---------------------------------------------------------------------------
extern "C" void kernel_launch(void* const* d_in, const int* in_sizes, int n_in,
                              void* d_out, int out_size, void* d_ws, size_t ws_size,
                              hipStream_t stream) {
    (void)in_sizes; (void)n_in; (void)out_size; (void)ws_size;
    const float* x1        = (const float*)d_in[0];
    const float* x2        = (const float*)d_in[1];
    const float* gamma     = (const float*)d_in[2];
    const float* beta      = (const float*)d_in[3];
    const float* proj      = (const float*)d_in[4];
    const float* halves    = (const float*)d_in[5];
    const float* diagonals = (const float*)d_in[6];
    const float* Wm        = (const float*)d_in[7];
    const float* bmix      = (const float*)d_in[8];
    float* out = (float*)d_out;

    u16* us    = (u16*)d_ws;
    u16* Xh    = us;                        // 4,194,304 u16
    u16* Pwh   = Xh + 4194304;              // 262,144
    u16* PPh   = Pwh + 262144;              // 2,097,152 (x1 rows, natural)
    u16* UTh   = PPh + 2097152;             // 524,288
    float* S   = (float*)(UTh + 524288);    // 65,536 f

    mega<<<dim3(512), 256, 0, stream>>>(x1, x2, gamma, beta, proj, halves,
                                        diagonals, Wm, bmix,
                                        Xh, Pwh, PPh, UTh, S, out);
}

// Round 8
// 357.126 us; speedup vs baseline: 68.6753x; 68.6753x over previous
//
#include <hip/hip_runtime.h>

typedef unsigned short u16;
typedef __attribute__((ext_vector_type(8))) short short8;   // 8 x bf16 (4 VGPRs)
typedef __attribute__((ext_vector_type(4))) float f32x4;

#define HALFN 2016

__device__ __forceinline__ u16 f2b_rn(float x) {         // round-nearest-even
    union { float f; unsigned u; } v; v.f = x;
    unsigned r = v.u + 0x7FFFu + ((v.u >> 16) & 1u);
    return (u16)(r >> 16);
}

__device__ __forceinline__ void gll16(const void* g, void* s) {
    __builtin_amdgcn_global_load_lds(
        (const __attribute__((address_space(1))) unsigned int*)g,
        (__attribute__((address_space(3))) unsigned int*)s, 16, 0, 0);
}

// Initial-value-independent grid barrier for an exactly-resident 512-block
// grid.  Per phase: 512 cells in the WORKSPACE (re-poisoned by the harness
// every iteration, so stale magics die between replays).  Each block stores
// MAGIC into its own cell; all 256 threads poll 2 cells each until every
// cell equals MAGIC (write-before-check => pre-launch content irrelevant).
// Bounded spin: a sync bug degrades to slow/wrong, never a hung container.
__device__ __forceinline__ void gbar(unsigned* cells, unsigned magic) {
    __threadfence();                              // release this phase's writes
    __syncthreads();
    if (threadIdx.x == 0)
        __hip_atomic_store(&cells[blockIdx.x], magic,
                           __ATOMIC_RELEASE, __HIP_MEMORY_SCOPE_AGENT);
    int ok = 0;
    for (int spins = 0; spins < 30000 && !ok; ++spins) {
        unsigned a = __hip_atomic_load(&cells[threadIdx.x],
                                       __ATOMIC_RELAXED, __HIP_MEMORY_SCOPE_AGENT);
        unsigned b = __hip_atomic_load(&cells[256 + threadIdx.x],
                                       __ATOMIC_RELAXED, __HIP_MEMORY_SCOPE_AGENT);
        ok = __syncthreads_and((a == magic) && (b == magic));
    }
    __threadfence();                              // acquire other blocks' writes
}

// Shared-memory union: phases are strictly sequential.  Max member 51.5 KB
// -> 2 blocks/CU uses 103 KB of 160 KB LDS (exact 512-block residency).
union SmemU {
    u16 g[2][12288];    // proj: 2x(A1|A2|B 64x64); out: 2x(A|B) uses 8192 each
    float pw[64][65];   // phase 0 Pw transpose tile
    struct { float Ms[64][65]; float Gs[64][68]; float Ts[64][68]; } tu;
};

// ---------------------------------------------------------------------------
// Single persistent kernel, 512 blocks x 256 threads (exactly 2 blocks/CU).
//   0: LN 16 rows/block -> Xh; blocks 0..63 also Pw transpose; S-zero slice.
//   1: proj GEMM (both seqs) + Gram partial -> S
//   2: M build, T = M@G, 16-mixer-row U chunk -> UTh
//   3: out = PP1 @ UT^T + bias
// ---------------------------------------------------------------------------
__global__ __launch_bounds__(256, 2) void mega(
    const float* __restrict__ x1, const float* __restrict__ x2,
    const float* __restrict__ gamma, const float* __restrict__ beta,
    const float* __restrict__ proj, const float* __restrict__ halves,
    const float* __restrict__ diagonals, const float* __restrict__ Wm,
    const float* __restrict__ bmix,
    u16* __restrict__ Xh, u16* __restrict__ Pwh, u16* __restrict__ PPh,
    u16* __restrict__ UTh, float* __restrict__ S, unsigned* __restrict__ bar,
    float* __restrict__ out)
{
    __shared__ __align__(16) SmemU sm;
    const int bid = blockIdx.x, t = threadIdx.x;
    const int lane = t & 63, w = t >> 6;

    // ===================== phase 0: LN + Pw prep + S zero =====================
    {
        if (t < 128) S[(size_t)bid * 128 + t] = 0.f;

        const float4 g0 = *(const float4*)&gamma[lane * 4];
        const float4 g1 = *(const float4*)&gamma[256 + lane * 4];
        const float4 b0 = *(const float4*)&beta[lane * 4];
        const float4 b1 = *(const float4*)&beta[256 + lane * 4];

        #pragma unroll
        for (int r = w; r < 16; r += 4) {                // wave per row
            const int row = bid * 16 + r;                // 0..8191
            const float* src = (row < 4096) ? (x1 + (size_t)row * 512)
                                            : (x2 + (size_t)(row - 4096) * 512);
            float4 v0 = *(const float4*)&src[lane * 4];
            float4 v1 = *(const float4*)&src[256 + lane * 4];
            float s  = v0.x + v0.y + v0.z + v0.w + v1.x + v1.y + v1.z + v1.w;
            float sq = v0.x * v0.x + v0.y * v0.y + v0.z * v0.z + v0.w * v0.w +
                       v1.x * v1.x + v1.y * v1.y + v1.z * v1.z + v1.w * v1.w;
            #pragma unroll
            for (int off = 32; off > 0; off >>= 1) {
                s  += __shfl_down(s, off);
                sq += __shfl_down(sq, off);
            }
            s  = __shfl(s, 0);
            sq = __shfl(sq, 0);
            float mu  = s * (1.0f / 512.0f);
            float var = sq * (1.0f / 512.0f) - mu * mu;
            float rs  = rsqrtf(var + 1e-5f);
            ushort4 h0, h1;
            h0.x = f2b_rn((v0.x - mu) * rs * g0.x + b0.x);
            h0.y = f2b_rn((v0.y - mu) * rs * g0.y + b0.y);
            h0.z = f2b_rn((v0.z - mu) * rs * g0.z + b0.z);
            h0.w = f2b_rn((v0.w - mu) * rs * g0.w + b0.w);
            h1.x = f2b_rn((v1.x - mu) * rs * g1.x + b1.x);
            h1.y = f2b_rn((v1.y - mu) * rs * g1.y + b1.y);
            h1.z = f2b_rn((v1.z - mu) * rs * g1.z + b1.z);
            h1.w = f2b_rn((v1.w - mu) * rs * g1.w + b1.w);
            *(ushort4*)&Xh[(size_t)row * 512 + lane * 4] = h0;
            *(ushort4*)&Xh[(size_t)row * 512 + 256 + lane * 4] = h1;
        }

        if (bid < 64) {                                  // 64 Pw tiles
            const int n = bid >> 3, c0 = (bid & 7) * 64;
            #pragma unroll
            for (int i = 0; i < 4; i++) {
                int flat = i * 256 + t;
                int c = flat >> 4, k4 = (flat & 15) * 4;
                float4 v = *(const float4*)&proj[(size_t)n * 32768 + (size_t)(c0 + c) * 64 + k4];
                sm.pw[c][k4 + 0] = v.x; sm.pw[c][k4 + 1] = v.y;
                sm.pw[c][k4 + 2] = v.z; sm.pw[c][k4 + 3] = v.w;
            }
            __syncthreads();
            #pragma unroll
            for (int i = 0; i < 16; i++) {
                int flat = i * 256 + t;
                int k = flat >> 6, c = flat & 63;
                Pwh[(size_t)(n * 64 + k) * 512 + c0 + c] = f2b_rn(sm.pw[c][k]);
            }
        }
    }
    gbar(bar, 0x5EED0001u);

    // ========== phase 1: proj GEMM (both seqs) + Gram partial -> S ==========
    {
        const int bx = bid & 63, n = bid >> 6;           // XCD = bid%8 = bx%8
        const int b = bx >> 5, v0 = (bx & 31) * 64;
        const u16* A1 = Xh + (size_t)(b * 2048 + v0) * 512;      // x1 rows
        const u16* A2 = A1 + (size_t)4096 * 512;                 // x2 rows
        const u16* Bp = Pwh + (size_t)(n * 64) * 512;
        const int wm = w & 1, wn = w >> 1;
        const int fr = lane & 15, q = lane >> 4;

        int aoff[2][2], boff[2][2];
        #pragma unroll
        for (int kc = 0; kc < 2; kc++) {
            #pragma unroll
            for (int i = 0; i < 2; i++) {
                int r = wm * 32 + i * 16 + fr;
                aoff[kc][i] = r * 64 + (((kc * 4 + q) ^ (r & 7)) * 8);
            }
            #pragma unroll
            for (int j = 0; j < 2; j++) {
                int r = wn * 32 + j * 16 + fr;
                boff[kc][j] = r * 64 + (((kc * 4 + q) ^ (r & 7)) * 8);
            }
        }

        auto stage = [&](int kt, u16* buf) {     // 6 global_load_lds / thread
            #pragma unroll
            for (int p = 0; p < 2; p++) {
                int o = p * 4096 + t * 16;
                int r = o >> 7;
                int c = ((o >> 4) & 7) ^ (r & 7);
                size_t g = (size_t)r * 512 + kt + c * 8;
                gll16(A1 + g, buf + (o >> 1));
                gll16(A2 + g, buf + 4096 + (o >> 1));
                gll16(Bp + g, buf + 8192 + (o >> 1));
            }
        };

        f32x4 acc1[2][2] = {}, acc2[2][2] = {};
        stage(0, sm.g[0]);
        __syncthreads();
        for (int k = 0; k < 8; k++) {
            u16* cur = sm.g[k & 1];
            if (k < 7) stage((k + 1) * 64, sm.g[(k & 1) ^ 1]);
            #pragma unroll
            for (int kc = 0; kc < 2; kc++) {
                short8 a1f[2], a2f[2], bf[2];
                #pragma unroll
                for (int i = 0; i < 2; i++) {
                    a1f[i] = *(const short8*)(cur + aoff[kc][i]);
                    a2f[i] = *(const short8*)(cur + 4096 + aoff[kc][i]);
                }
                #pragma unroll
                for (int j = 0; j < 2; j++)
                    bf[j] = *(const short8*)(cur + 8192 + boff[kc][j]);
                #pragma unroll
                for (int i = 0; i < 2; i++)
                    #pragma unroll
                    for (int j = 0; j < 2; j++) {
                        acc1[i][j] = __builtin_amdgcn_mfma_f32_16x16x32_bf16(a1f[i], bf[j], acc1[i][j], 0, 0, 0);
                        acc2[i][j] = __builtin_amdgcn_mfma_f32_16x16x32_bf16(a2f[i], bf[j], acc2[i][j], 0, 0, 0);
                    }
            }
            __syncthreads();
        }

        // epilogue: PPh (x1 natural) + transposed bf16 tiles into buf0.
        u16* lds = sm.g[0];
        #pragma unroll
        for (int i = 0; i < 2; i++) {
            const int mloc = wm * 32 + i * 16 + q * 4;
            #pragma unroll
            for (int j = 0; j < 2; j++) {
                const int c = wn * 32 + j * 16 + fr;     // head-local column
                u16 h1[4], h2[4];
                #pragma unroll
                for (int r = 0; r < 4; r++) {
                    h1[r] = f2b_rn(acc1[i][j][r]);
                    h2[r] = f2b_rn(acc2[i][j][r]);
                }
                #pragma unroll
                for (int r = 0; r < 4; r++)
                    PPh[(size_t)(b * 2048 + v0 + mloc + r) * 512 + n * 64 + c] = h1[r];
                const int sw = c * 64 + (((mloc >> 3) ^ (c & 7)) * 8) + (mloc & 7);
                ushort4 u1; u1.x = h1[0]; u1.y = h1[1]; u1.z = h1[2]; u1.w = h1[3];
                ushort4 u2; u2.x = h2[0]; u2.y = h2[1]; u2.z = h2[2]; u2.w = h2[3];
                *(ushort4*)&lds[sw] = u1;                // T1
                *(ushort4*)&lds[4096 + sw] = u2;         // T2
            }
        }
        __syncthreads();

        // partial Gram: G[j][k] = sum_{v local} T2[j][v] * T1[k][v]
        f32x4 accg[2][2] = {};
        #pragma unroll
        for (int ks = 0; ks < 2; ks++) {
            short8 ag[2], bg[2];
            #pragma unroll
            for (int i = 0; i < 2; i++) {
                int jr = wm * 32 + i * 16 + fr;
                ag[i] = *(const short8*)&lds[4096 + jr * 64 + (((ks * 4 + q) ^ (jr & 7)) * 8)];
            }
            #pragma unroll
            for (int j = 0; j < 2; j++) {
                int kr = wn * 32 + j * 16 + fr;
                bg[j] = *(const short8*)&lds[kr * 64 + (((ks * 4 + q) ^ (kr & 7)) * 8)];
            }
            #pragma unroll
            for (int i = 0; i < 2; i++)
                #pragma unroll
                for (int j = 0; j < 2; j++)
                    accg[i][j] = __builtin_amdgcn_mfma_f32_16x16x32_bf16(ag[i], bg[j], accg[i][j], 0, 0, 0);
        }
        float* Sb = S + (size_t)(b * 8 + n) * 4096;
        #pragma unroll
        for (int i = 0; i < 2; i++) {
            int jrow = wm * 32 + i * 16 + q * 4;
            #pragma unroll
            for (int j = 0; j < 2; j++) {
                int kk = wn * 32 + j * 16 + fr;
                #pragma unroll
                for (int r = 0; r < 4; r++)
                    atomicAdd(&Sb[(jrow + r) * 64 + kk], accg[i][j][r]);
            }
        }
    }
    gbar(bar + 512, 0x5EED0002u);

    // ============== phase 2: M build, T = M@G, U chunk -> UTh ==============
    {
        const int bn = bid >> 5, sub = bid & 31;
        const int b = bn >> 3, n = bn & 7;

        for (int idx = t; idx < 4096; idx += 256) {
            int r = idx >> 6, c = idx & 63;
            float val;
            if (r == c) {
                val = diagonals[n * 64 + r];
            } else {
                int rr = (r < c) ? r : c;
                int cc = (r < c) ? c : r;
                int h = rr * 63 - (rr * (rr - 1)) / 2 + (cc - rr - 1);
                val = halves[n * HALFN + h];
            }
            sm.tu.Ms[r][c] = val;
        }
        for (int idx = t; idx < 4096; idx += 256)
            sm.tu.Gs[idx >> 6][idx & 63] = S[(size_t)bn * 4096 + idx];
        __syncthreads();

        {   // T = M @ G : thread (k = t&63) computes chunk lq = t>>6 (16 cols)
            const int k = t & 63, lq = t >> 6;
            float a[16] = {};
            for (int j = 0; j < 64; j++) {
                float m = sm.tu.Ms[k][j];
                const float* gp = &sm.tu.Gs[j][lq * 16];
                #pragma unroll
                for (int u4 = 0; u4 < 4; u4++) {
                    float4 g4 = *(const float4*)&gp[u4 * 4];
                    a[u4 * 4 + 0] = fmaf(m, g4.x, a[u4 * 4 + 0]);
                    a[u4 * 4 + 1] = fmaf(m, g4.y, a[u4 * 4 + 1]);
                    a[u4 * 4 + 2] = fmaf(m, g4.z, a[u4 * 4 + 2]);
                    a[u4 * 4 + 3] = fmaf(m, g4.w, a[u4 * 4 + 3]);
                }
            }
            int pos = (lq ^ (k & 3)) * 16;               // swizzled chunk slot
            #pragma unroll
            for (int u4 = 0; u4 < 4; u4++) {
                float4 v4 = {a[u4 * 4 + 0], a[u4 * 4 + 1], a[u4 * 4 + 2], a[u4 * 4 + 3]};
                *(float4*)&sm.tu.Ts[k][pos + u4 * 4] = v4;
            }
        }
        __syncthreads();

        const int k2 = t & 63, cgp = t >> 6;
        const int c0 = sub * 16 + cgp * 4;               // 4 mixer rows/group
        float uacc[4] = {};
        #pragma unroll
        for (int kkc = 0; kkc < 4; kkc++) {
            const float* tp = &sm.tu.Ts[k2][(kkc ^ (k2 & 3)) * 16];
            float ts[16];
            #pragma unroll
            for (int u = 0; u < 4; u++) {
                float4 t4 = *(const float4*)&tp[u * 4];
                ts[u * 4 + 0] = t4.x; ts[u * 4 + 1] = t4.y;
                ts[u * 4 + 2] = t4.z; ts[u * 4 + 3] = t4.w;
            }
            #pragma unroll
            for (int i = 0; i < 4; i++) {
                const float* wrow = &Wm[(size_t)(c0 + i) * 512 + n * 64 + kkc * 16];
                #pragma unroll
                for (int u = 0; u < 4; u++) {
                    float4 w4 = *(const float4*)&wrow[u * 4];
                    uacc[i] = fmaf(ts[u * 4 + 0], w4.x, uacc[i]);
                    uacc[i] = fmaf(ts[u * 4 + 1], w4.y, uacc[i]);
                    uacc[i] = fmaf(ts[u * 4 + 2], w4.z, uacc[i]);
                    uacc[i] = fmaf(ts[u * 4 + 3], w4.w, uacc[i]);
                }
            }
        }
        #pragma unroll
        for (int i = 0; i < 4; i++)
            UTh[(size_t)b * 262144 + (size_t)(c0 + i) * 512 + n * 64 + k2] = f2b_rn(uacc[i]);
    }
    gbar(bar + 1024, 0x5EED0003u);

    // ================= phase 3: out = PP1 @ UT^T + bias =================
    {
        const int m0 = (bid & 31) * 64;                  // XCD = bid%8
        const int n0 = ((bid >> 5) & 7) * 64;
        const int b = bid >> 8;
        const u16* A  = PPh + (size_t)b * 2048 * 512;
        const u16* Bu = UTh + (size_t)b * 512 * 512;
        const int wm = w & 1, wn = w >> 1;
        const int fr = lane & 15, q = lane >> 4;

        int aoff[2][2], boff[2][2];
        #pragma unroll
        for (int kc = 0; kc < 2; kc++) {
            #pragma unroll
            for (int i = 0; i < 2; i++) {
                int r = wm * 32 + i * 16 + fr;
                aoff[kc][i] = r * 64 + (((kc * 4 + q) ^ (r & 7)) * 8);
            }
            #pragma unroll
            for (int j = 0; j < 2; j++) {
                int r = wn * 32 + j * 16 + fr;
                boff[kc][j] = r * 64 + (((kc * 4 + q) ^ (r & 7)) * 8);
            }
        }

        auto stage = [&](int kt, u16* buf) {     // 4 global_load_lds / thread
            #pragma unroll
            for (int p = 0; p < 2; p++) {
                int o = p * 4096 + t * 16;
                int r = o >> 7;
                int c = ((o >> 4) & 7) ^ (r & 7);
                gll16(A  + (size_t)(m0 + r) * 512 + kt + c * 8, buf + (o >> 1));
                gll16(Bu + (size_t)(n0 + r) * 512 + kt + c * 8, buf + 4096 + (o >> 1));
            }
        };

        f32x4 acc[2][2] = {};
        stage(0, sm.g[0]);
        __syncthreads();
        for (int k = 0; k < 8; k++) {
            u16* cur = sm.g[k & 1];
            if (k < 7) stage((k + 1) * 64, sm.g[(k & 1) ^ 1]);
            #pragma unroll
            for (int kc = 0; kc < 2; kc++) {
                short8 af[2], bf[2];
                #pragma unroll
                for (int i = 0; i < 2; i++)
                    af[i] = *(const short8*)(cur + aoff[kc][i]);
                #pragma unroll
                for (int j = 0; j < 2; j++)
                    bf[j] = *(const short8*)(cur + 4096 + boff[kc][j]);
                #pragma unroll
                for (int i = 0; i < 2; i++)
                    #pragma unroll
                    for (int j = 0; j < 2; j++)
                        acc[i][j] = __builtin_amdgcn_mfma_f32_16x16x32_bf16(af[i], bf[j], acc[i][j], 0, 0, 0);
            }
            __syncthreads();
        }

        #pragma unroll
        for (int i = 0; i < 2; i++) {
            int m = m0 + wm * 32 + i * 16 + q * 4;
            #pragma unroll
            for (int j = 0; j < 2; j++) {
                int n = n0 + wn * 32 + j * 16 + fr;
                float bv = bmix[n];
                #pragma unroll
                for (int r = 0; r < 4; r++)
                    out[(size_t)(b * 2048 + m + r) * 512 + n] = acc[i][j][r] + bv;
            }
        }
    }
}

// ---------------------------------------------------------------------------
extern "C" void kernel_launch(void* const* d_in, const int* in_sizes, int n_in,
                              void* d_out, int out_size, void* d_ws, size_t ws_size,
                              hipStream_t stream) {
    (void)in_sizes; (void)n_in; (void)out_size; (void)ws_size;
    const float* x1        = (const float*)d_in[0];
    const float* x2        = (const float*)d_in[1];
    const float* gamma     = (const float*)d_in[2];
    const float* beta      = (const float*)d_in[3];
    const float* proj      = (const float*)d_in[4];
    const float* halves    = (const float*)d_in[5];
    const float* diagonals = (const float*)d_in[6];
    const float* Wm        = (const float*)d_in[7];
    const float* bmix      = (const float*)d_in[8];
    float* out = (float*)d_out;

    u16* us    = (u16*)d_ws;
    u16* Xh    = us;                        // 4,194,304 u16
    u16* Pwh   = Xh + 4194304;              // 262,144
    u16* PPh   = Pwh + 262144;              // 2,097,152 (x1 rows, natural)
    u16* UTh   = PPh + 2097152;             // 524,288
    float* S   = (float*)(UTh + 524288);    // 65,536 f
    unsigned* bar = (unsigned*)(S + 65536); // 3 x 512 barrier cells (in ws)

    mega<<<dim3(512), 256, 0, stream>>>(x1, x2, gamma, beta, proj, halves,
                                        diagonals, Wm, bmix,
                                        Xh, Pwh, PPh, UTh, S, bar, out);
}

// Round 9
// 113.603 us; speedup vs baseline: 215.8904x; 3.1436x over previous
//
#include <hip/hip_runtime.h>

typedef unsigned short u16;
typedef __attribute__((ext_vector_type(8))) short short8;   // 8 x bf16 (4 VGPRs)
typedef __attribute__((ext_vector_type(4))) float f32x4;

#define HALFN 2016

__device__ __forceinline__ u16 f2b_rn(float x) {         // round-nearest-even
    union { float f; unsigned u; } v; v.f = x;
    unsigned r = v.u + 0x7FFFu + ((v.u >> 16) & 1u);
    return (u16)(r >> 16);
}

__device__ __forceinline__ void gll16(const void* g, void* s) {
    __builtin_amdgcn_global_load_lds(
        (const __attribute__((address_space(1))) unsigned int*)g,
        (__attribute__((address_space(3))) unsigned int*)s, 16, 0, 0);
}

// ---------------------------------------------------------------------------
// Kernel 1: blocks 0..2047: LayerNorm, one wave per row (4 rows/block);
// blocks 2048..2111: prep Pw (transpose, RN bf16); block 2112 zeroes S.
// ---------------------------------------------------------------------------
__global__ __launch_bounds__(256) void ln_prep(const float* __restrict__ x1,
                                               const float* __restrict__ x2,
                                               const float* __restrict__ gamma,
                                               const float* __restrict__ beta,
                                               const float* __restrict__ proj,
                                               u16* __restrict__ Xh,
                                               u16* __restrict__ Pwh,
                                               float* __restrict__ S) {
    const int bid = blockIdx.x, t = threadIdx.x;

    if (bid < 2048) {
        const int wv = t >> 6, lane = t & 63;
        const int row = bid * 4 + wv;             // 0..8191
        const float* src = (row < 4096) ? (x1 + (size_t)row * 512)
                                        : (x2 + (size_t)(row - 4096) * 512);
        float4 v0 = *(const float4*)&src[lane * 4];
        float4 v1 = *(const float4*)&src[256 + lane * 4];
        float s  = v0.x + v0.y + v0.z + v0.w + v1.x + v1.y + v1.z + v1.w;
        float sq = v0.x * v0.x + v0.y * v0.y + v0.z * v0.z + v0.w * v0.w +
                   v1.x * v1.x + v1.y * v1.y + v1.z * v1.z + v1.w * v1.w;
        #pragma unroll
        for (int off = 32; off > 0; off >>= 1) {
            s  += __shfl_down(s, off);
            sq += __shfl_down(sq, off);
        }
        s  = __shfl(s, 0);
        sq = __shfl(sq, 0);
        float mu  = s * (1.0f / 512.0f);
        float var = sq * (1.0f / 512.0f) - mu * mu;
        float rs  = rsqrtf(var + 1e-5f);
        float4 g0 = *(const float4*)&gamma[lane * 4];
        float4 g1 = *(const float4*)&gamma[256 + lane * 4];
        float4 b0 = *(const float4*)&beta[lane * 4];
        float4 b1 = *(const float4*)&beta[256 + lane * 4];
        ushort4 h0, h1;
        h0.x = f2b_rn((v0.x - mu) * rs * g0.x + b0.x);
        h0.y = f2b_rn((v0.y - mu) * rs * g0.y + b0.y);
        h0.z = f2b_rn((v0.z - mu) * rs * g0.z + b0.z);
        h0.w = f2b_rn((v0.w - mu) * rs * g0.w + b0.w);
        h1.x = f2b_rn((v1.x - mu) * rs * g1.x + b1.x);
        h1.y = f2b_rn((v1.y - mu) * rs * g1.y + b1.y);
        h1.z = f2b_rn((v1.z - mu) * rs * g1.z + b1.z);
        h1.w = f2b_rn((v1.w - mu) * rs * g1.w + b1.w);
        *(ushort4*)&Xh[(size_t)row * 512 + lane * 4] = h0;
        *(ushort4*)&Xh[(size_t)row * 512 + 256 + lane * 4] = h1;
    } else if (bid < 2112) {
        __shared__ float tile[64][65];
        const int id = bid - 2048;
        const int n = id >> 3, c0 = (id & 7) * 64;
        #pragma unroll
        for (int i = 0; i < 4; i++) {
            int flat = i * 256 + t;
            int c = flat >> 4, k4 = (flat & 15) * 4;
            float4 v = *(const float4*)&proj[(size_t)n * 32768 + (size_t)(c0 + c) * 64 + k4];
            tile[c][k4 + 0] = v.x; tile[c][k4 + 1] = v.y;
            tile[c][k4 + 2] = v.z; tile[c][k4 + 3] = v.w;
        }
        __syncthreads();
        #pragma unroll
        for (int i = 0; i < 16; i++) {
            int flat = i * 256 + t;
            int k = flat >> 6, c = flat & 63;
            Pwh[(size_t)(n * 64 + k) * 512 + c0 + c] = f2b_rn(tile[c][k]);
        }
    } else {
        float4 z = {0.f, 0.f, 0.f, 0.f};
        #pragma unroll
        for (int i = 0; i < 64; i++)
            *(float4*)&S[(size_t)(i * 256 + t) * 4] = z;
    }
}

// ---------------------------------------------------------------------------
// Kernel 2 (fused proj + Gram), 3-BUFFER COUNTED-VMCNT K-loop: stage(k+2)
// issued before compute(k); s_waitcnt vmcnt(6) + raw s_barrier per step --
// the (k+2)-prefetch stays in flight across the barrier (T3/T4, m201
// template).  Each block computes BOTH P1 and P2 64x64 tiles for
// (b, v-chunk, head n), sharing the B operand.  Epilogue: PPh write,
// transposed tiles -> LDS, Gram partial -> S via atomicAdd.
// grid (64 bx, 8 n): b = bx>>5, v0 = (bx&31)*64.  XCD = bx%8.
// LDS 3x24 KB = 72 KB -> 2 blocks/CU at grid 512.
// ---------------------------------------------------------------------------
__global__ __launch_bounds__(256) void proj_g_mfma(const u16* __restrict__ Xh,
                                                   const u16* __restrict__ Pwh,
                                                   u16* __restrict__ PPh,
                                                   float* __restrict__ S) {
    __shared__ u16 lds[36864];   // 3 x (A1 64x64 | A2 64x64 | B 64x64)
    const int bx = blockIdx.x;            // 0..63
    const int n  = blockIdx.y;            // 0..7
    const int b = bx >> 5, v0 = (bx & 31) * 64;
    const u16* A1 = Xh + (size_t)(b * 2048 + v0) * 512;          // x1 rows
    const u16* A2 = A1 + (size_t)4096 * 512;                     // x2 rows
    const u16* Bp = Pwh + (size_t)(n * 64) * 512;

    const int t = threadIdx.x, lane = t & 63, w = t >> 6, wm = w & 1, wn = w >> 1;
    const int fr = lane & 15, q = lane >> 4;

    int aoff[2][2], boff[2][2];
    #pragma unroll
    for (int kc = 0; kc < 2; kc++) {
        #pragma unroll
        for (int i = 0; i < 2; i++) {
            int r = wm * 32 + i * 16 + fr;
            aoff[kc][i] = r * 64 + (((kc * 4 + q) ^ (r & 7)) * 8);
        }
        #pragma unroll
        for (int j = 0; j < 2; j++) {
            int r = wn * 32 + j * 16 + fr;
            boff[kc][j] = r * 64 + (((kc * 4 + q) ^ (r & 7)) * 8);
        }
    }

    auto stage = [&](int kt, u16* buf) {     // 6 global_load_lds per thread
        #pragma unroll
        for (int p = 0; p < 2; p++) {
            int o = p * 4096 + t * 16;
            int r = o >> 7;
            int c = ((o >> 4) & 7) ^ (r & 7);
            size_t g = (size_t)r * 512 + kt + c * 8;
            gll16(A1 + g, buf + (o >> 1));
            gll16(A2 + g, buf + 4096 + (o >> 1));
            gll16(Bp + g, buf + 8192 + (o >> 1));
        }
    };

    f32x4 acc1[2][2] = {}, acc2[2][2] = {};
    stage(0, lds);
    stage(64, lds + 12288);
    asm volatile("s_waitcnt vmcnt(6)" ::: "memory");     // buf0 landed
    __builtin_amdgcn_s_barrier();
    __builtin_amdgcn_sched_barrier(0);
    for (int k = 0; k < 8; k++) {
        u16* cur = lds + (k % 3) * 12288;
        if (k < 6) stage((k + 2) * 64, lds + ((k + 2) % 3) * 12288);
        #pragma unroll
        for (int kc = 0; kc < 2; kc++) {
            short8 a1f[2], a2f[2], bf[2];
            #pragma unroll
            for (int i = 0; i < 2; i++) {
                a1f[i] = *(const short8*)(cur + aoff[kc][i]);
                a2f[i] = *(const short8*)(cur + 4096 + aoff[kc][i]);
            }
            #pragma unroll
            for (int j = 0; j < 2; j++)
                bf[j] = *(const short8*)(cur + 8192 + boff[kc][j]);
            #pragma unroll
            for (int i = 0; i < 2; i++)
                #pragma unroll
                for (int j = 0; j < 2; j++) {
                    acc1[i][j] = __builtin_amdgcn_mfma_f32_16x16x32_bf16(a1f[i], bf[j], acc1[i][j], 0, 0, 0);
                    acc2[i][j] = __builtin_amdgcn_mfma_f32_16x16x32_bf16(a2f[i], bf[j], acc2[i][j], 0, 0, 0);
                }
        }
        if (k < 6) { asm volatile("s_waitcnt vmcnt(6)" ::: "memory"); }   // (k+1)-buf done
        else       { asm volatile("s_waitcnt vmcnt(0)" ::: "memory"); }
        __builtin_amdgcn_s_barrier();
        __builtin_amdgcn_sched_barrier(0);
    }

    // epilogue: PPh (x1 natural) + transposed bf16 tiles into buf0.
    // T1 at lds[0..4096): T1[c][v] = P1[v][c]; T2 at lds[4096..8192).
    #pragma unroll
    for (int i = 0; i < 2; i++) {
        const int mloc = wm * 32 + i * 16 + q * 4;
        #pragma unroll
        for (int j = 0; j < 2; j++) {
            const int c = wn * 32 + j * 16 + fr;   // head-local column
            u16 h1[4], h2[4];
            #pragma unroll
            for (int r = 0; r < 4; r++) {
                h1[r] = f2b_rn(acc1[i][j][r]);
                h2[r] = f2b_rn(acc2[i][j][r]);
            }
            #pragma unroll
            for (int r = 0; r < 4; r++)
                PPh[(size_t)(b * 2048 + v0 + mloc + r) * 512 + n * 64 + c] = h1[r];
            const int sw = c * 64 + (((mloc >> 3) ^ (c & 7)) * 8) + (mloc & 7);
            ushort4 u1; u1.x = h1[0]; u1.y = h1[1]; u1.z = h1[2]; u1.w = h1[3];
            ushort4 u2; u2.x = h2[0]; u2.y = h2[1]; u2.z = h2[2]; u2.w = h2[3];
            *(ushort4*)&lds[sw] = u1;              // T1
            *(ushort4*)&lds[4096 + sw] = u2;       // T2
        }
    }
    __syncthreads();

    // partial Gram: G[j][k] = sum_{v local} T2[j][v] * T1[k][v]
    f32x4 accg[2][2] = {};
    #pragma unroll
    for (int ks = 0; ks < 2; ks++) {              // two K=32 steps over v=64
        short8 ag[2], bg[2];
        #pragma unroll
        for (int i = 0; i < 2; i++) {
            int jr = wm * 32 + i * 16 + fr;
            ag[i] = *(const short8*)&lds[4096 + jr * 64 + (((ks * 4 + q) ^ (jr & 7)) * 8)];
        }
        #pragma unroll
        for (int j = 0; j < 2; j++) {
            int kr = wn * 32 + j * 16 + fr;
            bg[j] = *(const short8*)&lds[kr * 64 + (((ks * 4 + q) ^ (kr & 7)) * 8)];
        }
        #pragma unroll
        for (int i = 0; i < 2; i++)
            #pragma unroll
            for (int j = 0; j < 2; j++)
                accg[i][j] = __builtin_amdgcn_mfma_f32_16x16x32_bf16(ag[i], bg[j], accg[i][j], 0, 0, 0);
    }
    float* Sb = S + (size_t)(b * 8 + n) * 4096;
    #pragma unroll
    for (int i = 0; i < 2; i++) {
        int jrow = wm * 32 + i * 16 + q * 4;
        #pragma unroll
        for (int j = 0; j < 2; j++) {
            int kk = wn * 32 + j * 16 + fr;
            #pragma unroll
            for (int r = 0; r < 4; r++)
                atomicAdd(&Sb[(jrow + r) * 64 + kk], accg[i][j][r]);
        }
    }
}

// ---------------------------------------------------------------------------
// Kernel 3 (fused tu), 512 blocks: bn = bid>>5, sub = bid&31.  Each block
// builds M, computes T = M@G (redundant across subs), then a 16-mixer-row
// U chunk -> UTh (RN bf16).
// ---------------------------------------------------------------------------
__global__ __launch_bounds__(256) void tu_kernel(const float* __restrict__ S,
                                                 const float* __restrict__ halves,
                                                 const float* __restrict__ diagonals,
                                                 const float* __restrict__ Wm,
                                                 u16* __restrict__ UTh) {
    __shared__ float Ms[64][65];
    __shared__ float Gs[64][68];
    __shared__ float Ts[64][68];
    const int bid = blockIdx.x, t = threadIdx.x;
    const int bn = bid >> 5, sub = bid & 31;
    const int b = bn >> 3, n = bn & 7;

    for (int idx = t; idx < 4096; idx += 256) {
        int r = idx >> 6, c = idx & 63;
        float val;
        if (r == c) {
            val = diagonals[n * 64 + r];
        } else {
            int rr = (r < c) ? r : c;
            int cc = (r < c) ? c : r;
            int h = rr * 63 - (rr * (rr - 1)) / 2 + (cc - rr - 1);
            val = halves[n * HALFN + h];
        }
        Ms[r][c] = val;
    }
    for (int idx = t; idx < 4096; idx += 256)
        Gs[idx >> 6][idx & 63] = S[(size_t)bn * 4096 + idx];
    __syncthreads();

    {   // T = M @ G : thread (k = t&63) computes chunk lq = t>>6 (16 cols)
        const int k = t & 63, lq = t >> 6;
        float a[16] = {};
        for (int j = 0; j < 64; j++) {
            float m = Ms[k][j];
            const float* gp = &Gs[j][lq * 16];
            #pragma unroll
            for (int u4 = 0; u4 < 4; u4++) {
                float4 g4 = *(const float4*)&gp[u4 * 4];
                a[u4 * 4 + 0] = fmaf(m, g4.x, a[u4 * 4 + 0]);
                a[u4 * 4 + 1] = fmaf(m, g4.y, a[u4 * 4 + 1]);
                a[u4 * 4 + 2] = fmaf(m, g4.z, a[u4 * 4 + 2]);
                a[u4 * 4 + 3] = fmaf(m, g4.w, a[u4 * 4 + 3]);
            }
        }
        int pos = (lq ^ (k & 3)) * 16;             // swizzled chunk slot
        #pragma unroll
        for (int u4 = 0; u4 < 4; u4++) {
            float4 v4 = {a[u4 * 4 + 0], a[u4 * 4 + 1], a[u4 * 4 + 2], a[u4 * 4 + 3]};
            *(float4*)&Ts[k][pos + u4 * 4] = v4;
        }
    }
    __syncthreads();

    const int k2 = t & 63, cgp = t >> 6;
    const int c0 = sub * 16 + cgp * 4;             // 4 mixer rows per group
    float uacc[4] = {};
    #pragma unroll
    for (int kkc = 0; kkc < 4; kkc++) {
        const float* tp = &Ts[k2][(kkc ^ (k2 & 3)) * 16];
        float ts[16];
        #pragma unroll
        for (int u = 0; u < 4; u++) {
            float4 t4 = *(const float4*)&tp[u * 4];
            ts[u * 4 + 0] = t4.x; ts[u * 4 + 1] = t4.y;
            ts[u * 4 + 2] = t4.z; ts[u * 4 + 3] = t4.w;
        }
        #pragma unroll
        for (int i = 0; i < 4; i++) {
            const float* wrow = &Wm[(size_t)(c0 + i) * 512 + n * 64 + kkc * 16];
            #pragma unroll
            for (int u = 0; u < 4; u++) {
                float4 w4 = *(const float4*)&wrow[u * 4];
                uacc[i] = fmaf(ts[u * 4 + 0], w4.x, uacc[i]);
                uacc[i] = fmaf(ts[u * 4 + 1], w4.y, uacc[i]);
                uacc[i] = fmaf(ts[u * 4 + 2], w4.z, uacc[i]);
                uacc[i] = fmaf(ts[u * 4 + 3], w4.w, uacc[i]);
            }
        }
    }
    #pragma unroll
    for (int i = 0; i < 4; i++)
        UTh[(size_t)b * 262144 + (size_t)(c0 + i) * 512 + n * 64 + k2] = f2b_rn(uacc[i]);
}

// ---------------------------------------------------------------------------
// Kernel 4: out[b] = PP1[b] @ UT^T + b_mixer.  64x64 tiles, 3-buffer
// counted-vmcnt BK=64 core (stage(k+2) before compute(k), vmcnt(4)).
// grid (32 m, 8 n, 2 b): XCD = m%8 -> A-slab reuse within an XCD L2.
// ---------------------------------------------------------------------------
__global__ __launch_bounds__(256) void gemm_out_mfma(const u16* __restrict__ PPh,
                                                     const u16* __restrict__ UTh,
                                                     const float* __restrict__ bias,
                                                     float* __restrict__ out) {
    __shared__ u16 lds[24576];   // 3 x (A 64x64 + B 64x64)
    const int b = blockIdx.z;
    const u16* A  = PPh + (size_t)b * 2048 * 512;
    const u16* Bu = UTh + (size_t)b * 512 * 512;
    const int m0 = blockIdx.x * 64, n0 = blockIdx.y * 64;
    const int t = threadIdx.x, lane = t & 63, w = t >> 6, wm = w & 1, wn = w >> 1;
    const int fr = lane & 15, q = lane >> 4;

    int aoff[2][2], boff[2][2];
    #pragma unroll
    for (int kc = 0; kc < 2; kc++) {
        #pragma unroll
        for (int i = 0; i < 2; i++) {
            int r = wm * 32 + i * 16 + fr;
            aoff[kc][i] = r * 64 + (((kc * 4 + q) ^ (r & 7)) * 8);
        }
        #pragma unroll
        for (int j = 0; j < 2; j++) {
            int r = wn * 32 + j * 16 + fr;
            boff[kc][j] = r * 64 + (((kc * 4 + q) ^ (r & 7)) * 8);
        }
    }

    auto stage = [&](int kt, u16* buf) {     // 4 global_load_lds per thread
        #pragma unroll
        for (int p = 0; p < 2; p++) {
            int o = p * 4096 + t * 16;
            int r = o >> 7;
            int c = ((o >> 4) & 7) ^ (r & 7);
            gll16(A  + (size_t)(m0 + r) * 512 + kt + c * 8, buf + (o >> 1));
            gll16(Bu + (size_t)(n0 + r) * 512 + kt + c * 8, buf + 4096 + (o >> 1));
        }
    };

    f32x4 acc[2][2] = {};
    stage(0, lds);
    stage(64, lds + 8192);
    asm volatile("s_waitcnt vmcnt(4)" ::: "memory");     // buf0 landed
    __builtin_amdgcn_s_barrier();
    __builtin_amdgcn_sched_barrier(0);
    for (int k = 0; k < 8; k++) {
        u16* cur = lds + (k % 3) * 8192;
        if (k < 6) stage((k + 2) * 64, lds + ((k + 2) % 3) * 8192);
        #pragma unroll
        for (int kc = 0; kc < 2; kc++) {
            short8 af[2], bf[2];
            #pragma unroll
            for (int i = 0; i < 2; i++)
                af[i] = *(const short8*)(cur + aoff[kc][i]);
            #pragma unroll
            for (int j = 0; j < 2; j++)
                bf[j] = *(const short8*)(cur + 4096 + boff[kc][j]);
            #pragma unroll
            for (int i = 0; i < 2; i++)
                #pragma unroll
                for (int j = 0; j < 2; j++)
                    acc[i][j] = __builtin_amdgcn_mfma_f32_16x16x32_bf16(af[i], bf[j], acc[i][j], 0, 0, 0);
        }
        if (k < 6) { asm volatile("s_waitcnt vmcnt(4)" ::: "memory"); }   // (k+1)-buf done
        else       { asm volatile("s_waitcnt vmcnt(0)" ::: "memory"); }
        __builtin_amdgcn_s_barrier();
        __builtin_amdgcn_sched_barrier(0);
    }

    #pragma unroll
    for (int i = 0; i < 2; i++) {
        int m = m0 + wm * 32 + i * 16 + q * 4;
        #pragma unroll
        for (int j = 0; j < 2; j++) {
            int n = n0 + wn * 32 + j * 16 + fr;
            float bv = bias[n];
            #pragma unroll
            for (int r = 0; r < 4; r++)
                out[(size_t)(b * 2048 + m + r) * 512 + n] = acc[i][j][r] + bv;
        }
    }
}

// ---------------------------------------------------------------------------
extern "C" void kernel_launch(void* const* d_in, const int* in_sizes, int n_in,
                              void* d_out, int out_size, void* d_ws, size_t ws_size,
                              hipStream_t stream) {
    (void)in_sizes; (void)n_in; (void)out_size; (void)ws_size;
    const float* x1        = (const float*)d_in[0];
    const float* x2        = (const float*)d_in[1];
    const float* gamma     = (const float*)d_in[2];
    const float* beta      = (const float*)d_in[3];
    const float* proj      = (const float*)d_in[4];
    const float* halves    = (const float*)d_in[5];
    const float* diagonals = (const float*)d_in[6];
    const float* Wm        = (const float*)d_in[7];
    const float* bmix      = (const float*)d_in[8];
    float* out = (float*)d_out;

    u16* us    = (u16*)d_ws;
    u16* Xh    = us;                        // 4,194,304 u16
    u16* Pwh   = Xh + 4194304;              // 262,144
    u16* PPh   = Pwh + 262144;              // 2,097,152 (x1 rows, natural)
    u16* UTh   = PPh + 2097152;             // 524,288
    float* S   = (float*)(UTh + 524288);    // 65,536 f

    ln_prep<<<dim3(2113), 256, 0, stream>>>(x1, x2, gamma, beta, proj, Xh, Pwh, S);
    proj_g_mfma<<<dim3(64, 8), 256, 0, stream>>>(Xh, Pwh, PPh, S);
    tu_kernel<<<dim3(512), 256, 0, stream>>>(S, halves, diagonals, Wm, UTh);
    gemm_out_mfma<<<dim3(32, 8, 2), 256, 0, stream>>>(PPh, UTh, bmix, out);
}